// Round 9
// baseline (767.121 us; speedup 1.0000x reference)
//
#include <hip/hip_runtime.h>
#include <hip/hip_bf16.h>
#include <cstdint>
#include <cstddef>

typedef unsigned short ushort_t;
typedef __bf16 bf16x8 __attribute__((ext_vector_type(8)));
typedef float floatx4 __attribute__((ext_vector_type(4)));

#define S_LEN 2048
#define DIN   512
#define DH    512
#define NHEAD 8
#define NBAT  4
#define NBH   32
#define HP    4096   // NHEAD*DH

// ---------- static device workspace ----------
#define MiB (1024ull * 1024ull)
#define WQT_OFF   (0ull)           //  4 MiB  WqT [8][512e][512d] bf16
#define WKT_OFF   (4ull  * MiB)    //  4 MiB
#define WVT_OFF   (8ull  * MiB)    //  4 MiB
#define WPT_OFF   (12ull * MiB)    //  4 MiB  WpT [512][4096] bf16
#define XBF_OFF   (16ull * MiB)    //  8 MiB  x bf16 [4][2048][512]
#define Q_OFF     (24ull * MiB)    // 64 MiB  [32][2048][512] bf16
#define K_OFF     (88ull * MiB)    // 64 MiB
#define VT_OFF    (152ull * MiB)   // 64 MiB  [32][512][2048] bf16
#define O_OFF     (216ull * MiB)   // 64 MiB  [4][2048][4096] bf16 (cat)
#define LSUM_OFF  (280ull * MiB)   // 128 KiB fp32 [16][2048]
#define P_OFF     (281ull * MiB)   // 128 MiB [16][2048][2048] bf16
#define WS_BYTES  (409ull * MiB)

__device__ __align__(256) unsigned char g_ws[WS_BYTES];

// ---------- helpers ----------
__device__ __forceinline__ ushort_t f2bf(float f) {
  union { float f; uint32_t u; } v; v.f = f;
  uint32_t r = v.u + 0x7fffu + ((v.u >> 16) & 1u);
  return (ushort_t)(r >> 16);
}

typedef __attribute__((address_space(3))) uint32_t lds_uint;
typedef __attribute__((address_space(1))) const uint32_t glb_uint;

__device__ __forceinline__ void async16(void* lds, const void* g) {
  __builtin_amdgcn_global_load_lds((glb_uint*)g, (lds_uint*)lds, 16, 0, 0);
}

// scheduling fence + hw barrier (used only OUTSIDE the GEMM main loop)
#define BBAR() do { \
    __builtin_amdgcn_sched_barrier(0); \
    __builtin_amdgcn_s_barrier(); \
    __builtin_amdgcn_sched_barrier(0); \
  } while (0)

// sched_group_barrier masks (LLVM SchedGroupMask)
#define SG_R(n) __builtin_amdgcn_sched_group_barrier(0x100, (n), 0) // DS_READ
#define SG_M(n) __builtin_amdgcn_sched_group_barrier(0x8,   (n), 0) // MFMA
#define SG_V(n) __builtin_amdgcn_sched_group_barrier(0x10,  (n), 0) // VMEM

// ============================================================================
// 256x256 GEMM core (frozen after r3-r7: 5 schedule variants all ~6300
// cyc/K-tile; source-level pipe overlap not reachable). Fine-interleaved
// single-barrier body, BK=64, 8 waves. LDS swizzle conflict-free (r1).
// ============================================================================

#define STG_A(dbuf, hh, kt) do { \
    const ushort_t* _g = gA + (size_t)(kt) * 64 + (size_t)(hh) * a128; \
    char* _s = sAh + (dbuf) * 32768 + (hh) * 16384; \
    async16(_s, _g); \
    async16(_s + 8192, _g + a64); \
  } while (0)

#define STG_B(dbuf, hh, kt) do { \
    const ushort_t* _g = gB + (size_t)(kt) * 64 + (size_t)(hh) * b128; \
    char* _s = sBh + (dbuf) * 32768 + (hh) * 16384; \
    async16(_s, _g); \
    async16(_s + 8192, _g + b64); \
  } while (0)

#define LDAF(fi) do { \
    const char* _b = (const char*)As + cur * 32768 + ((fi) >> 2) * 16384 \
                     + (((fi) & 3) << 11) + aoff0; \
    af[fi][0] = *(const bf16x8*)(_b + swz0); \
    af[fi][1] = *(const bf16x8*)(_b + swz1); \
  } while (0)

#define LDBF(fj) do { \
    const char* _b = (const char*)Bs + cur * 32768 + ((fj) >> 1) * 16384 \
                     + (((fj) & 1) << 11) + boff0; \
    bfr[fj][0] = *(const bf16x8*)(_b + swz0); \
    bfr[fj][1] = *(const bf16x8*)(_b + swz1); \
  } while (0)

#define MF2(q, ii, jj, ai, bj) do { \
    acc[q][ii][jj] = __builtin_amdgcn_mfma_f32_16x16x32_bf16(af[ai][0], bfr[bj][0], acc[q][ii][jj], 0, 0, 0); \
    acc[q][ii][jj] = __builtin_amdgcn_mfma_f32_16x16x32_bf16(af[ai][1], bfr[bj][1], acc[q][ii][jj], 0, 0, 0); \
  } while (0)

__device__ __forceinline__ void gemm256_core(
    const ushort_t* __restrict__ A, const ushort_t* __restrict__ Bt,
    int lda, int ldb, int kdim,
    ushort_t* As, ushort_t* Bs, floatx4 acc[4][4][2])
{
  const int t = threadIdx.x;
  const int w = t >> 6, l = t & 63;
  const int l15 = l & 15, lq = l >> 4;
  const int wq_r = w >> 2, wq_c = w & 3;

  const int r0 = t >> 3, c0 = t & 7;
  const ushort_t* gA = A + (size_t)r0 * lda + ((c0 ^ (r0 & 7)) << 3);
  const ushort_t* gB = Bt + (size_t)r0 * ldb + ((c0 ^ (r0 & 7)) << 3);
  const size_t a64 = (size_t)64 * lda, b64 = (size_t)64 * ldb;
  const size_t a128 = (size_t)128 * lda, b128 = (size_t)128 * ldb;
  char* sAh = (char*)As + (w << 10);
  char* sBh = (char*)Bs + (w << 10);

  const int aoff0 = ((wq_r << 6) + l15) << 7;
  const int boff0 = ((wq_c << 5) + l15) << 7;
  const int l7 = l15 & 7;
  const int swz0 = (lq ^ l7) << 4;
  const int swz1 = ((4 + lq) ^ l7) << 4;

  const int nt = kdim >> 6;

#pragma unroll
  for (int q = 0; q < 4; ++q)
#pragma unroll
    for (int i = 0; i < 4; ++i)
#pragma unroll
      for (int j = 0; j < 2; ++j)
        acc[q][i][j] = (floatx4){0.f, 0.f, 0.f, 0.f};

  // prologue: stage tile 0 fully into buf 0, drain, sync
  STG_A(0, 0, 0);
  STG_A(0, 1, 0);
  STG_B(0, 0, 0);
  STG_B(0, 1, 0);
  asm volatile("s_waitcnt vmcnt(0)" ::: "memory");
  BBAR();

  bf16x8 af[8][2], bfr[4][2];

#pragma unroll 1
  for (int tt = 0; tt < nt; ++tt) {
    const int cur = tt & 1, nxt = cur ^ 1;
    const bool more = (tt + 1 < nt);
    LDBF(0); LDBF(1); LDAF(0);
    SG_R(6);
    if (more) STG_A(nxt, 0, tt + 1);
    SG_V(2);
    LDAF(1); SG_R(2); MF2(0,0,0, 0,0); MF2(0,0,1, 0,1); SG_M(4);
    LDAF(2); SG_R(2); MF2(0,1,0, 1,0); MF2(0,1,1, 1,1); SG_M(4);
    LDAF(3); SG_R(2); MF2(0,2,0, 2,0); MF2(0,2,1, 2,1); SG_M(4);
    if (more) STG_A(nxt, 1, tt + 1);
    SG_V(2);
    LDBF(2); SG_R(2); MF2(0,3,0, 3,0); MF2(0,3,1, 3,1); SG_M(4);
    LDBF(3); SG_R(2); MF2(1,0,0, 0,2); MF2(1,1,0, 1,2); SG_M(4);
    if (more) STG_B(nxt, 0, tt + 1);
    SG_V(2);
    LDAF(4); SG_R(2); MF2(1,2,0, 2,2); MF2(1,3,0, 3,2); SG_M(4);
    LDAF(5); SG_R(2); MF2(1,0,1, 0,3); MF2(1,1,1, 1,3); SG_M(4);
    LDAF(6); SG_R(2); MF2(1,2,1, 2,3); MF2(1,3,1, 3,3); SG_M(4);
    if (more) STG_B(nxt, 1, tt + 1);
    SG_V(2);
    LDAF(7); SG_R(2); MF2(2,0,0, 4,2); MF2(2,1,0, 5,2); SG_M(4);
    MF2(2,2,0, 6,2); MF2(2,3,0, 7,2); SG_M(4);
    MF2(2,0,1, 4,3); MF2(2,1,1, 5,3); SG_M(4);
    MF2(2,2,1, 6,3); MF2(2,3,1, 7,3); SG_M(4);
    MF2(3,0,0, 4,0); MF2(3,1,0, 5,0); SG_M(4);
    MF2(3,2,0, 6,0); MF2(3,3,0, 7,0); SG_M(4);
    MF2(3,0,1, 4,1); MF2(3,1,1, 5,1); SG_M(4);
    MF2(3,2,1, 6,1); MF2(3,3,1, 7,1); SG_M(4);
    asm volatile("s_waitcnt vmcnt(0)" ::: "memory");
    __builtin_amdgcn_s_barrier();
  }
}

// bounce-tile byte offset: row-major [m][n] bf16 256x256, 16B-chunk swizzled
// by m&7 (kills m-stride-512B bank aliasing; residual ~2-way = free).
__device__ __forceinline__ int bounce_addr(int m, int n) {
  return m * 512 + (((n >> 3) ^ (m & 7)) << 4) + (n & 7) * 2;
}

// ---------- fp32 -> bf16 bulk convert into g_ws ----------
__global__ __launch_bounds__(256) void convert_f32_bf16(
    const float* __restrict__ src, size_t dstOff, int n)
{
  ushort_t* dst = (ushort_t*)(g_ws + dstOff);
  int i = (blockIdx.x * 256 + threadIdx.x) * 4;
  if (i >= n) return;
  float4 v = *(const float4*)(src + i);
  ushort_t o[4] = {f2bf(v.x), f2bf(v.y), f2bf(v.z), f2bf(v.w)};
  *(uint2*)(dst + i) = *(const uint2*)o;
}

// ---------- fp32 [R][C] -> bf16 [C][R] transpose into g_ws, batched over z ----
__global__ __launch_bounds__(256) void transpose_f32_bf16(
    const float* __restrict__ src, size_t dstOff, int R, int C)
{
  __shared__ ushort_t tile[32][33];
  ushort_t* dst = (ushort_t*)(g_ws + dstOff) + (size_t)blockIdx.z * R * C;
  src += (size_t)blockIdx.z * R * C;
  int r0 = blockIdx.y * 32, c0 = blockIdx.x * 32;
  int tx = threadIdx.x & 31, ty = threadIdx.x >> 5;
  for (int i = ty; i < 32; i += 8)
    tile[i][tx] = f2bf(src[(size_t)(r0 + i) * C + (c0 + tx)]);
  __syncthreads();
  for (int i = ty; i < 32; i += 8)
    dst[(size_t)(c0 + i) * R + (r0 + tx)] = tile[tx][i];
}

// ---------- zero lsum (16*2048 fp32 = 128 KiB) ----------
__global__ __launch_bounds__(256) void zero_lsum()
{
  float* lsum = (float*)(g_ws + LSUM_OFF);
  int i = (blockIdx.x * 256 + threadIdx.x) * 4;
  *(float4*)(lsum + i) = (float4){0.f, 0.f, 0.f, 0.f};
}

// ---------- zero the fp32 output (proj accumulates atomically) ----------
__global__ __launch_bounds__(256) void zero_out(float* __restrict__ out)
{
  int i = (blockIdx.x * 256 + threadIdx.x) * 4;
  *(float4*)(out + i) = (float4){0.f, 0.f, 0.f, 0.f};
}

// ---------- QKV projection (256² core): z in [0,96) ----------
__global__ __launch_bounds__(512, 2) void qkv_gemm(
    const float* __restrict__ bq, const float* __restrict__ bk,
    const float* __restrict__ bv)
{
  __shared__ __align__(16) ushort_t SH[65536];   // 128 KiB
  ushort_t* As = SH;
  ushort_t* Bs = SH + 32768;
  const int z = blockIdx.z;
  const int bh = z & 31, sel = z >> 5, b = bh >> 3, h = bh & 7;
  const size_t wOff = (sel == 0) ? WQT_OFF : (sel == 1) ? WKT_OFF : WVT_OFF;
  const float* bias = ((sel == 0) ? bq : (sel == 1) ? bk : bv) + h * DH;
  const int tileM = blockIdx.y * 256, tileN = blockIdx.x * 256;

  const ushort_t* A  = (const ushort_t*)(g_ws + XBF_OFF)
                       + ((size_t)b * S_LEN + tileM) * DIN;
  const ushort_t* Bt = (const ushort_t*)(g_ws + wOff)
                       + ((size_t)h * DH + tileN) * DIN;
  floatx4 acc[4][4][2];
  gemm256_core(A, Bt, DIN, DIN, DIN, As, Bs, acc);

  const int t = threadIdx.x, w = t >> 6, l = t & 63;
  const int l15 = l & 15, lq = l >> 4;
  const int wq_r = w >> 2, wq_c = w & 3;
  const int QM[4] = {0, 0, 1, 1}, QN[4] = {0, 1, 1, 0};
  char* SB = (char*)SH;
  BBAR();   // core done with SH; safe to reuse

  if (sel == 2) {
    // ---- VT transpose-bounce (column-major pack, r3-proven) ----
#pragma unroll
    for (int q = 0; q < 4; ++q) {
#pragma unroll
      for (int j = 0; j < 2; ++j) {
        const int nl = QN[q] * 128 + wq_c * 32 + j * 16 + l15;
        const float bsn = bias[tileN + nl];
#pragma unroll
        for (int i = 0; i < 4; ++i) {
          const int ml = QM[q] * 128 + wq_r * 64 + i * 16 + lq * 4;
          ushort_t pk[4];
#pragma unroll
          for (int r = 0; r < 4; ++r) pk[r] = f2bf(acc[q][i][j][r] + bsn);
          const int byte = nl * 512 + (((ml >> 3) ^ (nl & 7)) << 4) + (ml & 7) * 2;
          *(uint2*)(SB + byte) = *(const uint2*)pk;
        }
      }
    }
    BBAR();
    ushort_t* VTb = (ushort_t*)(g_ws + VT_OFF)
                    + ((size_t)bh * DH + tileN) * S_LEN + tileM;
#pragma unroll
    for (int s = 0; s < 16; ++s) {
      const int nl = (w << 5) + (s << 1) + (l >> 5);
      const int c  = l & 31;
      const uint4 v = *(const uint4*)(SB + nl * 512 + ((c ^ (nl & 7)) << 4));
      *(uint4*)(VTb + (size_t)nl * S_LEN + c * 8) = v;
    }
  } else {
    // ---- Q/K row-major bounce: b16 writes -> coalesced dwordx4 rows ----
#pragma unroll
    for (int q = 0; q < 4; ++q) {
#pragma unroll
      for (int j = 0; j < 2; ++j) {
        const int nl = QN[q] * 128 + wq_c * 32 + j * 16 + l15;
        const float bsn = bias[tileN + nl];
#pragma unroll
        for (int i = 0; i < 4; ++i) {
#pragma unroll
          for (int r = 0; r < 4; ++r) {
            const int ml = QM[q] * 128 + wq_r * 64 + i * 16 + lq * 4 + r;
            *(ushort_t*)(SB + bounce_addr(ml, nl)) = f2bf(acc[q][i][j][r] + bsn);
          }
        }
      }
    }
    BBAR();
    ushort_t* Dg = (ushort_t*)(g_ws + ((sel == 0) ? Q_OFF : K_OFF))
                   + ((size_t)bh * S_LEN + tileM) * DH + tileN;
#pragma unroll
    for (int s = 0; s < 16; ++s) {
      const int ml = (w << 5) + (s << 1) + (l >> 5);
      const int c  = l & 31;
      const uint4 v = *(const uint4*)(SB + ml * 512 + ((c ^ (ml & 7)) << 4));
      *(uint4*)(Dg + (size_t)ml * DH + c * 8) = v;
    }
  }
}

// ---------- scores + masked exp + fused row-sum ----------
// 8-head chunk, 1-D grid 512, hl8 = bid&7 -> XCD. P-store bounced via LDS.
__global__ __launch_bounds__(512, 2) void scores_kernel(
    const int* __restrict__ mask, int cbase)
{
  __shared__ __align__(16) ushort_t SH[65536];
  ushort_t* As = SH;
  ushort_t* Bs = SH + 32768;
  const int bid = blockIdx.x;
  const int hl8 = bid & 7, tl = bid >> 3;            // tl in [0,64)
  const int tileM = (tl & 7) * 256, tileN = (tl >> 3) * 256;  // N-major sweep
  const int bh = cbase + hl8, b = bh >> 3;
  const int hl16 = bh & 15;                          // index into P/lsum chunk

  const ushort_t* A  = (const ushort_t*)(g_ws + Q_OFF)
                       + ((size_t)bh * S_LEN + tileM) * DH;
  const ushort_t* Bt = (const ushort_t*)(g_ws + K_OFF)
                       + ((size_t)bh * S_LEN + tileN) * DH;
  floatx4 acc[4][4][2];
  gemm256_core(A, Bt, DH, DH, DH, As, Bs, acc);

  const float scale = 0.04419417382415922f;  // 1/sqrt(512)
  const int t = threadIdx.x, w = t >> 6, l = t & 63;
  const int l15 = l & 15, lq = l >> 4;
  const int wq_r = w >> 2, wq_c = w & 3;
  const int QM[4] = {0, 0, 1, 1}, QN[4] = {0, 1, 1, 0};
  const int* mask_b = mask + (size_t)b * S_LEN;
  float* lsum = (float*)(g_ws + LSUM_OFF);
  char* SB = (char*)SH;
  BBAR();   // core done with SH

  float rsum[2][4][4];
#pragma unroll
  for (int qm = 0; qm < 2; ++qm)
#pragma unroll
    for (int i = 0; i < 4; ++i)
#pragma unroll
      for (int r = 0; r < 4; ++r) rsum[qm][i][r] = 0.f;

#pragma unroll
  for (int q = 0; q < 4; ++q) {
#pragma unroll
    for (int j = 0; j < 2; ++j) {
      const int nl = QN[q] * 128 + wq_c * 32 + j * 16 + l15;
      const int mv = mask_b[tileN + nl];
#pragma unroll
      for (int i = 0; i < 4; ++i) {
#pragma unroll
        for (int r = 0; r < 4; ++r) {
          const int ml = QM[q] * 128 + wq_r * 64 + i * 16 + lq * 4 + r;
          float s = fminf(acc[q][i][j][r] * scale, 30.f);  // clamp: no inf
          const float p = mv ? __expf(s) : 0.f;
          rsum[QM[q]][i][r] += p;
          *(ushort_t*)(SB + bounce_addr(ml, nl)) = f2bf(p);
        }
      }
    }
  }
  BBAR();
  ushort_t* Pg = (ushort_t*)(g_ws + P_OFF) + (size_t)hl16 * S_LEN * S_LEN
                 + (size_t)tileM * S_LEN + tileN;
#pragma unroll
  for (int s = 0; s < 16; ++s) {
    const int ml = (w << 5) + (s << 1) + (l >> 5);
    const int c  = l & 31;
    const uint4 v = *(const uint4*)(SB + ml * 512 + ((c ^ (ml & 7)) << 4));
    *(uint4*)(Pg + (size_t)ml * S_LEN + c * 8) = v;
  }
#pragma unroll
  for (int qm = 0; qm < 2; ++qm) {
#pragma unroll
    for (int i = 0; i < 4; ++i) {
#pragma unroll
      for (int r = 0; r < 4; ++r) {
        float v = rsum[qm][i][r];
        v += __shfl_xor(v, 1);
        v += __shfl_xor(v, 2);
        v += __shfl_xor(v, 4);
        v += __shfl_xor(v, 8);
        if (l15 == 0) {
          const int m = tileM + qm * 128 + wq_r * 64 + i * 16 + lq * 4 + r;
          atomicAdd(&lsum[(size_t)hl16 * S_LEN + m], v);
        }
      }
    }
  }
}

// ---------- P*V, divide by rowsum, bounced cat-layout O store ----------
__global__ __launch_bounds__(512, 2) void pv_kernel(int c0)
{
  __shared__ __align__(16) ushort_t SH[65536];
  ushort_t* As = SH;
  ushort_t* Bs = SH + 32768;
  const int hl = blockIdx.z, bh = c0 + hl, b = bh >> 3, h = bh & 7;
  const int tileM = blockIdx.y * 256, tileN = blockIdx.x * 256;

  const ushort_t* A  = (const ushort_t*)(g_ws + P_OFF)
                       + (size_t)hl * S_LEN * S_LEN + (size_t)tileM * S_LEN;
  const ushort_t* Bt = (const ushort_t*)(g_ws + VT_OFF)
                       + ((size_t)bh * DH + tileN) * S_LEN;
  floatx4 acc[4][4][2];
  gemm256_core(A, Bt, S_LEN, S_LEN, S_LEN, As, Bs, acc);

  const float* lsum = (const float*)(g_ws + LSUM_OFF);
  const int t = threadIdx.x, w = t >> 6, l = t & 63;
  const int l15 = l & 15, lq = l >> 4;
  const int wq_r = w >> 2, wq_c = w & 3;
  const int QM[4] = {0, 0, 1, 1}, QN[4] = {0, 1, 1, 0};
  char* SB = (char*)SH;
  BBAR();   // core done with SH

#pragma unroll
  for (int q = 0; q < 4; ++q) {
#pragma unroll
    for (int i = 0; i < 4; ++i) {
#pragma unroll
      for (int r = 0; r < 4; ++r) {
        const int ml = QM[q] * 128 + wq_r * 64 + i * 16 + lq * 4 + r;
        const float lv = lsum[(size_t)hl * S_LEN + tileM + ml];
        const float inv = (lv > 1e-20f) ? 1.0f / lv : 0.f;
#pragma unroll
        for (int j = 0; j < 2; ++j) {
          const int nl = QN[q] * 128 + wq_c * 32 + j * 16 + l15;
          *(ushort_t*)(SB + bounce_addr(ml, nl)) = f2bf(acc[q][i][j][r] * inv);
        }
      }
    }
  }
  BBAR();
  ushort_t* Og = (ushort_t*)(g_ws + O_OFF)
                 + ((size_t)b * S_LEN + tileM) * HP + h * DH + tileN;
#pragma unroll
  for (int s = 0; s < 16; ++s) {
    const int ml = (w << 5) + (s << 1) + (l >> 5);
    const int c  = l & 31;
    const uint4 v = *(const uint4*)(SB + ml * 512 + ((c ^ (ml & 7)) << 4));
    *(uint4*)(Og + (size_t)ml * HP + c * 8) = v;
  }
}

// ---------- out projection, 256² core + split-K=4 (r8-proven) ----------
__global__ __launch_bounds__(512, 2) void proj_kernel(
    const float* __restrict__ bp, float* __restrict__ out)
{
  __shared__ __align__(16) ushort_t SH[65536];
  ushort_t* As = SH;
  ushort_t* Bs = SH + 32768;
  const int tileM = blockIdx.y * 256, tileN = blockIdx.x * 256;
  const int ks = blockIdx.z;

  const ushort_t* A  = (const ushort_t*)(g_ws + O_OFF)
                       + (size_t)tileM * HP + ks * 1024;
  const ushort_t* Bt = (const ushort_t*)(g_ws + WPT_OFF)
                       + (size_t)tileN * HP + ks * 1024;
  floatx4 acc[4][4][2];
  gemm256_core(A, Bt, HP, HP, 1024, As, Bs, acc);

  const int t = threadIdx.x, w = t >> 6, l = t & 63;
  const int l15 = l & 15, lq = l >> 4;
  const int wq_r = w >> 2, wq_c = w & 3;
  const int QM[4] = {0, 0, 1, 1}, QN[4] = {0, 1, 1, 0};
#pragma unroll
  for (int q = 0; q < 4; ++q) {
#pragma unroll
    for (int j = 0; j < 2; ++j) {
      const int n = tileN + QN[q] * 128 + wq_c * 32 + j * 16 + l15;
      const float bsn = (ks == 0) ? bp[n] : 0.f;
#pragma unroll
      for (int i = 0; i < 4; ++i) {
#pragma unroll
        for (int r = 0; r < 4; ++r) {
          const int m = tileM + QM[q] * 128 + wq_r * 64 + i * 16 + lq * 4 + r;
          atomicAdd(&out[(size_t)m * DH + n], acc[q][i][j][r] + bsn);
        }
      }
    }
  }
}

// ---------- host ----------
extern "C" void kernel_launch(void* const* d_in, const int* in_sizes, int n_in,
                              void* d_out, int out_size, void* d_ws, size_t ws_size,
                              hipStream_t stream) {
  const float* x  = (const float*)d_in[0];
  const int*   msk= (const int*)d_in[1];
  const float* Wq = (const float*)d_in[2];
  const float* bq = (const float*)d_in[3];
  const float* Wk = (const float*)d_in[4];
  const float* bk = (const float*)d_in[5];
  const float* Wv = (const float*)d_in[6];
  const float* bv = (const float*)d_in[7];
  const float* Wp = (const float*)d_in[8];
  const float* bp = (const float*)d_in[9];
  float* out = (float*)d_out;

  // x -> bf16 (all batches)
  convert_f32_bf16<<<dim3(NBAT * S_LEN * DIN / 1024), 256, 0, stream>>>(
      x, XBF_OFF, NBAT * S_LEN * DIN);

  // weight transposes (fp32 -> bf16); zero output for proj's atomic accum
  transpose_f32_bf16<<<dim3(16, 16, NHEAD), 256, 0, stream>>>(Wq, WQT_OFF, DIN, DH);
  transpose_f32_bf16<<<dim3(16, 16, NHEAD), 256, 0, stream>>>(Wk, WKT_OFF, DIN, DH);
  transpose_f32_bf16<<<dim3(16, 16, NHEAD), 256, 0, stream>>>(Wv, WVT_OFF, DIN, DH);
  transpose_f32_bf16<<<dim3(16, 128, 1),    256, 0, stream>>>(Wp, WPT_OFF, HP, DH);
  zero_out<<<dim3(NBAT * S_LEN * DH / 1024), 256, 0, stream>>>(out);

  // Q/K/V^T for all 32 (b,h): 256² tiles -> grid (2, 8, 96)
  qkv_gemm<<<dim3(2, 8, 3 * NBH), 512, 0, stream>>>(bq, bk, bv);

  // attention: scores in 8-head XCD-local chunks, pv in 16-head chunks
  for (int c16 = 0; c16 < NBH; c16 += 16) {
    zero_lsum<<<dim3(32), 256, 0, stream>>>();
    scores_kernel<<<dim3(512), 512, 0, stream>>>(msk, c16);
    scores_kernel<<<dim3(512), 512, 0, stream>>>(msk, c16 + 8);
    pv_kernel<<<dim3(2, 8, 16), 512, 0, stream>>>(c16);
  }

  // final projection: split-K=4 atomic accumulate (out pre-zeroed)
  proj_kernel<<<dim3(2, 32, 4), 512, 0, stream>>>(bp, out);
}

// Round 10
// 674.639 us; speedup vs baseline: 1.1371x; 1.1371x over previous
//
#include <hip/hip_runtime.h>
#include <hip/hip_bf16.h>
#include <cstdint>
#include <cstddef>

typedef unsigned short ushort_t;
typedef __bf16 bf16x8 __attribute__((ext_vector_type(8)));
typedef float floatx4 __attribute__((ext_vector_type(4)));

#define S_LEN 2048
#define DIN   512
#define DH    512
#define NHEAD 8
#define NBAT  4
#define NBH   32
#define HP    4096   // NHEAD*DH

// ---------- static device workspace ----------
#define MiB (1024ull * 1024ull)
#define WQT_OFF   (0ull)           //  4 MiB  WqT [8][512e][512d] bf16
#define WKT_OFF   (4ull  * MiB)    //  4 MiB
#define WVT_OFF   (8ull  * MiB)    //  4 MiB
#define WPT_OFF   (12ull * MiB)    //  4 MiB  WpT [512][4096] bf16
#define XBF_OFF   (16ull * MiB)    //  8 MiB  x bf16 [4][2048][512]
#define Q_OFF     (24ull * MiB)    // 64 MiB  [32][2048][512] bf16
#define K_OFF     (88ull * MiB)    // 64 MiB
#define VT_OFF    (152ull * MiB)   // 64 MiB  [32][512][2048] bf16
#define O_OFF     (216ull * MiB)   // 64 MiB  [4][2048][4096] bf16 (cat)
#define LSUM_OFF  (280ull * MiB)   // 128 KiB fp32 [16][2048]
#define P_OFF     (281ull * MiB)   // 128 MiB [16][2048][2048] bf16
#define WS_BYTES  (409ull * MiB)

__device__ __align__(256) unsigned char g_ws[WS_BYTES];

// ---------- helpers ----------
__device__ __forceinline__ ushort_t f2bf(float f) {
  union { float f; uint32_t u; } v; v.f = f;
  uint32_t r = v.u + 0x7fffu + ((v.u >> 16) & 1u);
  return (ushort_t)(r >> 16);
}

typedef __attribute__((address_space(3))) uint32_t lds_uint;
typedef __attribute__((address_space(1))) const uint32_t glb_uint;

__device__ __forceinline__ void async16(void* lds, const void* g) {
  __builtin_amdgcn_global_load_lds((glb_uint*)g, (lds_uint*)lds, 16, 0, 0);
}

// scheduling fence + hw barrier (only used OUTSIDE the 8-phase main loop)
#define BBAR() do { \
    __builtin_amdgcn_sched_barrier(0); \
    __builtin_amdgcn_s_barrier(); \
    __builtin_amdgcn_sched_barrier(0); \
  } while (0)

// raw barrier for the 8-phase loop — NO sched fences
#define RBAR() __builtin_amdgcn_s_barrier()

// ============================================================================
// 256x256 GEMM core — r6 8-phase structure (best measured config: 686 us
// total). BK=64, 512 thr = 8 waves, 2 K-tiles per iteration. Per phase:
// {ds-reads for one 16-MFMA quadrant; stage ONE half-tile into a slot whose
// last reader passed >=1 closing barrier ago; s_barrier; setprio(1); 16 MFMA;
// setprio(0); s_barrier}. vmcnt(4) only at ph3/ph7 closings; vmcnt(0) only
// in the last iteration. Slot-liveness/drain arithmetic verified (r6 notes).
// LDS swizzle (r1-verified conflict-free): 16B-chunk c of row r at c^(r&7);
// global SOURCE pre-swizzled, LDS dest linear. Requires kdim % 128 == 0.
// ============================================================================

#define STG_A(dbuf, hh, kt) do { \
    const ushort_t* _g = gA + (size_t)(kt) * 64 + (size_t)(hh) * a128; \
    char* _s = sAh + (dbuf) * 32768 + (hh) * 16384; \
    async16(_s, _g); \
    async16(_s + 8192, _g + a64); \
  } while (0)

#define STG_B(dbuf, hh, kt) do { \
    const ushort_t* _g = gB + (size_t)(kt) * 64 + (size_t)(hh) * b128; \
    char* _s = sBh + (dbuf) * 32768 + (hh) * 16384; \
    async16(_s, _g); \
    async16(_s + 8192, _g + b64); \
  } while (0)

#define LD_A2(dst, buf, qm) do { \
    const char* _b = (const char*)As + (buf) * 32768 + (qm) * 16384 + aoff0; \
    _Pragma("unroll") \
    for (int _i = 0; _i < 4; ++_i) { \
      dst[_i][0] = *(const bf16x8*)(_b + (_i << 11) + swz0); \
      dst[_i][1] = *(const bf16x8*)(_b + (_i << 11) + swz1); \
    } } while (0)

#define LD_B2(dst, buf, qn) do { \
    const char* _b = (const char*)Bs + (buf) * 32768 + (qn) * 16384 + boff0; \
    _Pragma("unroll") \
    for (int _j = 0; _j < 2; ++_j) { \
      dst[_j][0] = *(const bf16x8*)(_b + (_j << 11) + swz0); \
      dst[_j][1] = *(const bf16x8*)(_b + (_j << 11) + swz1); \
    } } while (0)

#define MM(q, AF, BF) do { \
    _Pragma("unroll") \
    for (int _i = 0; _i < 4; ++_i) { \
      _Pragma("unroll") \
      for (int _j = 0; _j < 2; ++_j) { \
        acc[q][_i][_j] = __builtin_amdgcn_mfma_f32_16x16x32_bf16(AF[_i][0], BF[_j][0], acc[q][_i][_j], 0, 0, 0); \
        acc[q][_i][_j] = __builtin_amdgcn_mfma_f32_16x16x32_bf16(AF[_i][1], BF[_j][1], acc[q][_i][_j], 0, 0, 0); \
      } \
    } \
  } while (0)

// one phase: reads already issued by caller; stage; bar; prio-MFMA; bar
#define PHASE(q, AF, BF, STMT) do { \
    STMT; \
    RBAR(); \
    __builtin_amdgcn_s_setprio(1); \
    MM(q, AF, BF); \
    __builtin_amdgcn_s_setprio(0); \
    RBAR(); \
  } while (0)

__device__ __forceinline__ void gemm256_core(
    const ushort_t* __restrict__ A, const ushort_t* __restrict__ Bt,
    int lda, int ldb, int kdim,
    ushort_t* As, ushort_t* Bs, floatx4 acc[4][4][2])
{
  const int t = threadIdx.x;
  const int w = t >> 6, l = t & 63;
  const int l15 = l & 15, lq = l >> 4;
  const int wq_r = w >> 2, wq_c = w & 3;

  const int r0 = t >> 3, c0 = t & 7;
  const ushort_t* gA = A + (size_t)r0 * lda + ((c0 ^ (r0 & 7)) << 3);
  const ushort_t* gB = Bt + (size_t)r0 * ldb + ((c0 ^ (r0 & 7)) << 3);
  const size_t a64 = (size_t)64 * lda, b64 = (size_t)64 * ldb;
  const size_t a128 = (size_t)128 * lda, b128 = (size_t)128 * ldb;
  char* sAh = (char*)As + (w << 10);
  char* sBh = (char*)Bs + (w << 10);

  const int aoff0 = ((wq_r << 6) + l15) << 7;
  const int boff0 = ((wq_c << 5) + l15) << 7;
  const int l7 = l15 & 7;
  const int swz0 = (lq ^ l7) << 4;
  const int swz1 = ((4 + lq) ^ l7) << 4;

  const int nt = kdim >> 6;   // even for all our shapes (8/16/32)

#pragma unroll
  for (int q = 0; q < 4; ++q)
#pragma unroll
    for (int i = 0; i < 4; ++i)
#pragma unroll
      for (int j = 0; j < 2; ++j)
        acc[q][i][j] = (floatx4){0.f, 0.f, 0.f, 0.f};

  // prologue: tile0 all 4 halves + A0/B0 of tile1; keep newest 2 in flight
  STG_A(0, 0, 0);
  STG_B(0, 0, 0);
  STG_B(0, 1, 0);
  STG_A(0, 1, 0);
  STG_A(1, 0, 1);
  STG_B(1, 0, 1);
  asm volatile("s_waitcnt vmcnt(4)" ::: "memory");
  RBAR();

  bf16x8 a[4][2], b0[2][2], b1[2][2];

#pragma unroll 1
  for (int T = 0; T < nt; T += 2) {
    const bool more = (T + 2 < nt);
    // ---- ph0: tile T q(0,0); stage B1(T+1)
    LD_A2(a, 0, 0);
    LD_B2(b0, 0, 0);
    PHASE(0, a, b0, STG_B(1, 1, T + 1));
    // ---- ph1: tile T q(0,1); stage A1(T+1)
    LD_B2(b1, 0, 1);
    PHASE(1, a, b1, STG_A(1, 1, T + 1));
    // ---- ph2: tile T q(1,1); stage A0(T+2)
    LD_A2(a, 0, 1);
    PHASE(2, a, b1, if (more) STG_A(0, 0, T + 2));
    // ---- ph3: tile T q(1,0); stage B0(T+2); boundary vmcnt
    {
      if (more) STG_B(0, 0, T + 2);
      RBAR();
      __builtin_amdgcn_s_setprio(1);
      MM(3, a, b0);
      __builtin_amdgcn_s_setprio(0);
      if (more) asm volatile("s_waitcnt vmcnt(4)" ::: "memory");
      else      asm volatile("s_waitcnt vmcnt(0)" ::: "memory");
      RBAR();
    }
    // ---- ph4: tile T+1 q(0,0); stage B1(T+2)
    LD_A2(a, 1, 0);
    LD_B2(b0, 1, 0);
    PHASE(0, a, b0, if (more) STG_B(0, 1, T + 2));
    // ---- ph5: tile T+1 q(0,1); stage A1(T+2)
    LD_B2(b1, 1, 1);
    PHASE(1, a, b1, if (more) STG_A(0, 1, T + 2));
    // ---- ph6: tile T+1 q(1,1); stage A0(T+3)
    LD_A2(a, 1, 1);
    PHASE(2, a, b1, if (more) STG_A(1, 0, T + 3));
    // ---- ph7: tile T+1 q(1,0); stage B0(T+3); boundary vmcnt
    {
      if (more) STG_B(1, 0, T + 3);
      RBAR();
      __builtin_amdgcn_s_setprio(1);
      MM(3, a, b0);
      __builtin_amdgcn_s_setprio(0);
      if (more) asm volatile("s_waitcnt vmcnt(4)" ::: "memory");
      else      asm volatile("s_waitcnt vmcnt(0)" ::: "memory");
      RBAR();
    }
  }
}

// ---------- fp32 -> bf16 bulk convert into g_ws ----------
__global__ __launch_bounds__(256) void convert_f32_bf16(
    const float* __restrict__ src, size_t dstOff, int n)
{
  ushort_t* dst = (ushort_t*)(g_ws + dstOff);
  int i = (blockIdx.x * 256 + threadIdx.x) * 4;
  if (i >= n) return;
  float4 v = *(const float4*)(src + i);
  ushort_t o[4] = {f2bf(v.x), f2bf(v.y), f2bf(v.z), f2bf(v.w)};
  *(uint2*)(dst + i) = *(const uint2*)o;
}

// ---------- fp32 [R][C] -> bf16 [C][R] transpose into g_ws, batched over z ----
__global__ __launch_bounds__(256) void transpose_f32_bf16(
    const float* __restrict__ src, size_t dstOff, int R, int C)
{
  __shared__ ushort_t tile[32][33];
  ushort_t* dst = (ushort_t*)(g_ws + dstOff) + (size_t)blockIdx.z * R * C;
  src += (size_t)blockIdx.z * R * C;
  int r0 = blockIdx.y * 32, c0 = blockIdx.x * 32;
  int tx = threadIdx.x & 31, ty = threadIdx.x >> 5;
  for (int i = ty; i < 32; i += 8)
    tile[i][tx] = f2bf(src[(size_t)(r0 + i) * C + (c0 + tx)]);
  __syncthreads();
  for (int i = ty; i < 32; i += 8)
    dst[(size_t)(c0 + i) * R + (r0 + tx)] = tile[tx][i];
}

// ---------- zero lsum (16*2048 fp32 = 128 KiB) ----------
__global__ __launch_bounds__(256) void zero_lsum()
{
  float* lsum = (float*)(g_ws + LSUM_OFF);
  int i = (blockIdx.x * 256 + threadIdx.x) * 4;
  *(float4*)(lsum + i) = (float4){0.f, 0.f, 0.f, 0.f};
}

// ---------- zero the fp32 output (proj accumulates atomically) ----------
__global__ __launch_bounds__(256) void zero_out(float* __restrict__ out)
{
  int i = (blockIdx.x * 256 + threadIdx.x) * 4;
  *(float4*)(out + i) = (float4){0.f, 0.f, 0.f, 0.f};
}

// ---------- QKV projection (256² core): z in [0,96) ----------
__global__ __launch_bounds__(512, 2) void qkv_gemm(
    const float* __restrict__ bq, const float* __restrict__ bk,
    const float* __restrict__ bv)
{
  __shared__ __align__(16) ushort_t SH[65536];   // 128 KiB
  ushort_t* As = SH;
  ushort_t* Bs = SH + 32768;
  const int z = blockIdx.z;
  const int bh = z & 31, sel = z >> 5, b = bh >> 3, h = bh & 7;
  const size_t wOff = (sel == 0) ? WQT_OFF : (sel == 1) ? WKT_OFF : WVT_OFF;
  const float* bias = ((sel == 0) ? bq : (sel == 1) ? bk : bv) + h * DH;
  const int tileM = blockIdx.y * 256, tileN = blockIdx.x * 256;

  const ushort_t* A  = (const ushort_t*)(g_ws + XBF_OFF)
                       + ((size_t)b * S_LEN + tileM) * DIN;
  const ushort_t* Bt = (const ushort_t*)(g_ws + wOff)
                       + ((size_t)h * DH + tileN) * DIN;
  floatx4 acc[4][4][2];
  gemm256_core(A, Bt, DIN, DIN, DIN, As, Bs, acc);

  const int t = threadIdx.x, w = t >> 6, l = t & 63;
  const int l15 = l & 15, lq = l >> 4;
  const int wq_r = w >> 2, wq_c = w & 3;
  const int QM[4] = {0, 0, 1, 1}, QN[4] = {0, 1, 1, 0};

  if (sel == 2) {
    // ---- VT transpose-bounce (r3-proven: fixes 4KB-stride scatter) ----
    char* SB = (char*)SH;
    BBAR();   // core's reads all done; safe to reuse SH
#pragma unroll
    for (int q = 0; q < 4; ++q) {
#pragma unroll
      for (int j = 0; j < 2; ++j) {
        const int nl = QN[q] * 128 + wq_c * 32 + j * 16 + l15;
        const float bsn = bias[tileN + nl];
#pragma unroll
        for (int i = 0; i < 4; ++i) {
          const int ml = QM[q] * 128 + wq_r * 64 + i * 16 + lq * 4;
          ushort_t pk[4];
#pragma unroll
          for (int r = 0; r < 4; ++r) pk[r] = f2bf(acc[q][i][j][r] + bsn);
          const int byte = nl * 512 + (((ml >> 3) ^ (nl & 7)) << 4) + (ml & 7) * 2;
          *(uint2*)(SB + byte) = *(const uint2*)pk;
        }
      }
    }
    BBAR();
    ushort_t* VTb = (ushort_t*)(g_ws + VT_OFF)
                    + ((size_t)bh * DH + tileN) * S_LEN + tileM;
#pragma unroll
    for (int s = 0; s < 16; ++s) {
      const int nl = (w << 5) + (s << 1) + (l >> 5);
      const int c  = l & 31;
      const uint4 v = *(const uint4*)(SB + nl * 512 + ((c ^ (nl & 7)) << 4));
      *(uint4*)(VTb + (size_t)nl * S_LEN + c * 8) = v;
    }
  } else {
    // ---- Q/K direct stores (r9 proved bouncing these is a regression) ----
    ushort_t* Db = (ushort_t*)(g_ws + ((sel == 0) ? Q_OFF : K_OFF));
#pragma unroll
    for (int q = 0; q < 4; ++q) {
#pragma unroll
      for (int j = 0; j < 2; ++j) {
        const int n = tileN + QN[q] * 128 + wq_c * 32 + j * 16 + l15;
        const float bsn = bias[n];
#pragma unroll
        for (int i = 0; i < 4; ++i) {
#pragma unroll
          for (int r = 0; r < 4; ++r) {
            const int m = tileM + QM[q] * 128 + wq_r * 64 + i * 16 + lq * 4 + r;
            Db[((size_t)bh * S_LEN + m) * DH + n] = f2bf(acc[q][i][j][r] + bsn);
          }
        }
      }
    }
  }
}

// ---------- scores + masked exp + fused row-sum, head chunk [c0, c0+16) ----
__global__ __launch_bounds__(512, 2) void scores_kernel(
    const int* __restrict__ mask, int c0)
{
  __shared__ __align__(16) ushort_t SH[65536];
  ushort_t* As = SH;
  ushort_t* Bs = SH + 32768;
  const int hl = blockIdx.z, bh = c0 + hl, b = bh >> 3;
  const int tileM = blockIdx.y * 256, tileN = blockIdx.x * 256;

  const ushort_t* A  = (const ushort_t*)(g_ws + Q_OFF)
                       + ((size_t)bh * S_LEN + tileM) * DH;
  const ushort_t* Bt = (const ushort_t*)(g_ws + K_OFF)
                       + ((size_t)bh * S_LEN + tileN) * DH;
  floatx4 acc[4][4][2];
  gemm256_core(A, Bt, DH, DH, DH, As, Bs, acc);

  const float scale = 0.04419417382415922f;  // 1/sqrt(512)
  const int t = threadIdx.x, w = t >> 6, l = t & 63;
  const int l15 = l & 15, lq = l >> 4;
  const int wq_r = w >> 2, wq_c = w & 3;
  const int QM[4] = {0, 0, 1, 1}, QN[4] = {0, 1, 1, 0};
  ushort_t* Pp = (ushort_t*)(g_ws + P_OFF) + (size_t)hl * S_LEN * S_LEN;
  const int* mask_b = mask + (size_t)b * S_LEN;
  float* lsum = (float*)(g_ws + LSUM_OFF);

  float rsum[2][4][4];
#pragma unroll
  for (int qm = 0; qm < 2; ++qm)
#pragma unroll
    for (int i = 0; i < 4; ++i)
#pragma unroll
      for (int r = 0; r < 4; ++r) rsum[qm][i][r] = 0.f;

#pragma unroll
  for (int q = 0; q < 4; ++q) {
#pragma unroll
    for (int j = 0; j < 2; ++j) {
      const int n = tileN + QN[q] * 128 + wq_c * 32 + j * 16 + l15;
      const int mv = mask_b[n];
#pragma unroll
      for (int i = 0; i < 4; ++i) {
#pragma unroll
        for (int r = 0; r < 4; ++r) {
          const int m = tileM + QM[q] * 128 + wq_r * 64 + i * 16 + lq * 4 + r;
          float s = fminf(acc[q][i][j][r] * scale, 30.f);  // clamp: no inf
          const float p = mv ? __expf(s) : 0.f;
          rsum[QM[q]][i][r] += p;
          Pp[(size_t)m * S_LEN + n] = f2bf(p);
        }
      }
    }
  }
#pragma unroll
  for (int qm = 0; qm < 2; ++qm) {
#pragma unroll
    for (int i = 0; i < 4; ++i) {
#pragma unroll
      for (int r = 0; r < 4; ++r) {
        float v = rsum[qm][i][r];
        v += __shfl_xor(v, 1);
        v += __shfl_xor(v, 2);
        v += __shfl_xor(v, 4);
        v += __shfl_xor(v, 8);
        if (l15 == 0) {
          const int m = tileM + qm * 128 + wq_r * 64 + i * 16 + lq * 4 + r;
          atomicAdd(&lsum[(size_t)hl * S_LEN + m], v);
        }
      }
    }
  }
}

// ---------- P*V, divide by rowsum, store cat-layout O ----------
__global__ __launch_bounds__(512, 2) void pv_kernel(int c0)
{
  __shared__ __align__(16) ushort_t SH[65536];
  ushort_t* As = SH;
  ushort_t* Bs = SH + 32768;
  const int hl = blockIdx.z, bh = c0 + hl, b = bh >> 3, h = bh & 7;
  const int tileM = blockIdx.y * 256, tileN = blockIdx.x * 256;

  const ushort_t* A  = (const ushort_t*)(g_ws + P_OFF)
                       + (size_t)hl * S_LEN * S_LEN + (size_t)tileM * S_LEN;
  const ushort_t* Bt = (const ushort_t*)(g_ws + VT_OFF)
                       + ((size_t)bh * DH + tileN) * S_LEN;
  floatx4 acc[4][4][2];
  gemm256_core(A, Bt, S_LEN, S_LEN, S_LEN, As, Bs, acc);

  const float* lsum = (const float*)(g_ws + LSUM_OFF);
  ushort_t* Ob = (ushort_t*)(g_ws + O_OFF);
  const int t = threadIdx.x, w = t >> 6, l = t & 63;
  const int l15 = l & 15, lq = l >> 4;
  const int wq_r = w >> 2, wq_c = w & 3;
  const int QM[4] = {0, 0, 1, 1}, QN[4] = {0, 1, 1, 0};
#pragma unroll
  for (int q = 0; q < 4; ++q) {
#pragma unroll
    for (int i = 0; i < 4; ++i) {
#pragma unroll
      for (int r = 0; r < 4; ++r) {
        const int m = tileM + QM[q] * 128 + wq_r * 64 + i * 16 + lq * 4 + r;
        const float lv = lsum[(size_t)hl * S_LEN + m];
        const float inv = (lv > 1e-20f) ? 1.0f / lv : 0.f;
#pragma unroll
        for (int j = 0; j < 2; ++j) {
          const int n = tileN + QN[q] * 128 + wq_c * 32 + j * 16 + l15;
          Ob[((size_t)b * S_LEN + m) * HP + h * DH + n] =
              f2bf(acc[q][i][j][r] * inv);
        }
      }
    }
  }
}

// ---------- out projection, 256² core + split-K=4 (r8-proven) ----------
// out[8192][512] += Ob[8192][4096] * WpT^T + bp  (bias in split 0 only).
// Grid (2 N, 32 M, 4 ksplit) = 256 blocks; each K=1024 (nt=16, even).
__global__ __launch_bounds__(512, 2) void proj_kernel(
    const float* __restrict__ bp, float* __restrict__ out)
{
  __shared__ __align__(16) ushort_t SH[65536];
  ushort_t* As = SH;
  ushort_t* Bs = SH + 32768;
  const int tileM = blockIdx.y * 256, tileN = blockIdx.x * 256;
  const int ks = blockIdx.z;

  const ushort_t* A  = (const ushort_t*)(g_ws + O_OFF)
                       + (size_t)tileM * HP + ks * 1024;
  const ushort_t* Bt = (const ushort_t*)(g_ws + WPT_OFF)
                       + (size_t)tileN * HP + ks * 1024;
  floatx4 acc[4][4][2];
  gemm256_core(A, Bt, HP, HP, 1024, As, Bs, acc);

  const int t = threadIdx.x, w = t >> 6, l = t & 63;
  const int l15 = l & 15, lq = l >> 4;
  const int wq_r = w >> 2, wq_c = w & 3;
  const int QM[4] = {0, 0, 1, 1}, QN[4] = {0, 1, 1, 0};
#pragma unroll
  for (int q = 0; q < 4; ++q) {
#pragma unroll
    for (int j = 0; j < 2; ++j) {
      const int n = tileN + QN[q] * 128 + wq_c * 32 + j * 16 + l15;
      const float bsn = (ks == 0) ? bp[n] : 0.f;
#pragma unroll
      for (int i = 0; i < 4; ++i) {
#pragma unroll
        for (int r = 0; r < 4; ++r) {
          const int m = tileM + QM[q] * 128 + wq_r * 64 + i * 16 + lq * 4 + r;
          atomicAdd(&out[(size_t)m * DH + n], acc[q][i][j][r] + bsn);
        }
      }
    }
  }
}

// ---------- host ----------
extern "C" void kernel_launch(void* const* d_in, const int* in_sizes, int n_in,
                              void* d_out, int out_size, void* d_ws, size_t ws_size,
                              hipStream_t stream) {
  const float* x  = (const float*)d_in[0];
  const int*   msk= (const int*)d_in[1];
  const float* Wq = (const float*)d_in[2];
  const float* bq = (const float*)d_in[3];
  const float* Wk = (const float*)d_in[4];
  const float* bk = (const float*)d_in[5];
  const float* Wv = (const float*)d_in[6];
  const float* bv = (const float*)d_in[7];
  const float* Wp = (const float*)d_in[8];
  const float* bp = (const float*)d_in[9];
  float* out = (float*)d_out;

  // x -> bf16 (all batches)
  convert_f32_bf16<<<dim3(NBAT * S_LEN * DIN / 1024), 256, 0, stream>>>(
      x, XBF_OFF, NBAT * S_LEN * DIN);

  // weight transposes (fp32 -> bf16); zero output for proj's atomic accum
  transpose_f32_bf16<<<dim3(16, 16, NHEAD), 256, 0, stream>>>(Wq, WQT_OFF, DIN, DH);
  transpose_f32_bf16<<<dim3(16, 16, NHEAD), 256, 0, stream>>>(Wk, WKT_OFF, DIN, DH);
  transpose_f32_bf16<<<dim3(16, 16, NHEAD), 256, 0, stream>>>(Wv, WVT_OFF, DIN, DH);
  transpose_f32_bf16<<<dim3(16, 128, 1),    256, 0, stream>>>(Wp, WPT_OFF, HP, DH);
  zero_out<<<dim3(NBAT * S_LEN * DH / 1024), 256, 0, stream>>>(out);

  // Q/K/V^T for all 32 (b,h): 256² tiles -> grid (2, 8, 96)
  qkv_gemm<<<dim3(2, 8, 3 * NBH), 512, 0, stream>>>(bq, bk, bv);

  // attention in chunks of 16 heads (P chunk = 128 MiB, L3-resident)
  for (int c0 = 0; c0 < NBH; c0 += 16) {
    zero_lsum<<<dim3(32), 256, 0, stream>>>();
    scores_kernel<<<dim3(8, 8, 16), 512, 0, stream>>>(msk, c0);
    pv_kernel<<<dim3(2, 8, 16), 512, 0, stream>>>(c0);
  }

  // final projection: split-K=4 atomic accumulate (out pre-zeroed)
  proj_kernel<<<dim3(2, 32, 4), 512, 0, stream>>>(bp, out);
}

// Round 11
// 652.768 us; speedup vs baseline: 1.1752x; 1.0335x over previous
//
#include <hip/hip_runtime.h>
#include <hip/hip_bf16.h>
#include <cstdint>
#include <cstddef>

typedef unsigned short ushort_t;
typedef __bf16 bf16x8 __attribute__((ext_vector_type(8)));
typedef float floatx4 __attribute__((ext_vector_type(4)));

#define S_LEN 2048
#define DIN   512
#define DH    512
#define NHEAD 8
#define NBAT  4
#define NBH   32
#define HP    4096   // NHEAD*DH

// ---------- static device workspace ----------
#define MiB (1024ull * 1024ull)
#define WQT_OFF   (0ull)           //  4 MiB  WqT [8][512e][512d] bf16
#define WKT_OFF   (4ull  * MiB)    //  4 MiB
#define WVT_OFF   (8ull  * MiB)    //  4 MiB
#define WPT_OFF   (12ull * MiB)    //  4 MiB  WpT [512][4096] bf16
#define XBF_OFF   (16ull * MiB)    //  8 MiB  x bf16 [4][2048][512]
#define Q_OFF     (24ull * MiB)    // 64 MiB  [32][2048][512] bf16
#define K_OFF     (88ull * MiB)    // 64 MiB
#define VT_OFF    (152ull * MiB)   // 64 MiB  [32][512][2048] bf16
#define O_OFF     (216ull * MiB)   // 64 MiB  [4][2048][4096] bf16 (cat)
#define LSUM_OFF  (280ull * MiB)   // 256 KiB fp32 [32][2048] (global head idx)
#define P_OFF     (281ull * MiB)   // 128 MiB [16][2048][2048] bf16
#define PART_OFF  (409ull * MiB)   // 64 MiB  fp32 [4][8192][512] proj partials
#define WS_BYTES  (473ull * MiB)

__device__ __align__(256) unsigned char g_ws[WS_BYTES];

// ---------- helpers ----------
__device__ __forceinline__ ushort_t f2bf(float f) {
  union { float f; uint32_t u; } v; v.f = f;
  uint32_t r = v.u + 0x7fffu + ((v.u >> 16) & 1u);
  return (ushort_t)(r >> 16);
}

typedef __attribute__((address_space(3))) uint32_t lds_uint;
typedef __attribute__((address_space(1))) const uint32_t glb_uint;

__device__ __forceinline__ void async16(void* lds, const void* g) {
  __builtin_amdgcn_global_load_lds((glb_uint*)g, (lds_uint*)lds, 16, 0, 0);
}

// scheduling fence + hw barrier (only used OUTSIDE the 8-phase main loop)
#define BBAR() do { \
    __builtin_amdgcn_sched_barrier(0); \
    __builtin_amdgcn_s_barrier(); \
    __builtin_amdgcn_sched_barrier(0); \
  } while (0)

// raw barrier for the 8-phase loop — NO sched fences
#define RBAR() __builtin_amdgcn_s_barrier()

// ============================================================================
// 256x256 GEMM core — r6 8-phase structure (best measured config). BK=64,
// 512 thr = 8 waves, 2 K-tiles per iteration. Per phase: {ds-reads for one
// 16-MFMA quadrant; stage ONE half-tile into a slot whose last reader passed
// >=1 closing barrier ago; s_barrier; setprio(1); 16 MFMA; setprio(0);
// s_barrier}. vmcnt(4) only at ph3/ph7 closings; vmcnt(0) only in the last
// iteration. Slot-liveness/drain arithmetic verified (r6 notes).
// LDS swizzle (r1-verified conflict-free): 16B-chunk c of row r at c^(r&7);
// global SOURCE pre-swizzled, LDS dest linear. Requires kdim % 128 == 0.
// ============================================================================

#define STG_A(dbuf, hh, kt) do { \
    const ushort_t* _g = gA + (size_t)(kt) * 64 + (size_t)(hh) * a128; \
    char* _s = sAh + (dbuf) * 32768 + (hh) * 16384; \
    async16(_s, _g); \
    async16(_s + 8192, _g + a64); \
  } while (0)

#define STG_B(dbuf, hh, kt) do { \
    const ushort_t* _g = gB + (size_t)(kt) * 64 + (size_t)(hh) * b128; \
    char* _s = sBh + (dbuf) * 32768 + (hh) * 16384; \
    async16(_s, _g); \
    async16(_s + 8192, _g + b64); \
  } while (0)

#define LD_A2(dst, buf, qm) do { \
    const char* _b = (const char*)As + (buf) * 32768 + (qm) * 16384 + aoff0; \
    _Pragma("unroll") \
    for (int _i = 0; _i < 4; ++_i) { \
      dst[_i][0] = *(const bf16x8*)(_b + (_i << 11) + swz0); \
      dst[_i][1] = *(const bf16x8*)(_b + (_i << 11) + swz1); \
    } } while (0)

#define LD_B2(dst, buf, qn) do { \
    const char* _b = (const char*)Bs + (buf) * 32768 + (qn) * 16384 + boff0; \
    _Pragma("unroll") \
    for (int _j = 0; _j < 2; ++_j) { \
      dst[_j][0] = *(const bf16x8*)(_b + (_j << 11) + swz0); \
      dst[_j][1] = *(const bf16x8*)(_b + (_j << 11) + swz1); \
    } } while (0)

#define MM(q, AF, BF) do { \
    _Pragma("unroll") \
    for (int _i = 0; _i < 4; ++_i) { \
      _Pragma("unroll") \
      for (int _j = 0; _j < 2; ++_j) { \
        acc[q][_i][_j] = __builtin_amdgcn_mfma_f32_16x16x32_bf16(AF[_i][0], BF[_j][0], acc[q][_i][_j], 0, 0, 0); \
        acc[q][_i][_j] = __builtin_amdgcn_mfma_f32_16x16x32_bf16(AF[_i][1], BF[_j][1], acc[q][_i][_j], 0, 0, 0); \
      } \
    } \
  } while (0)

// one phase: reads already issued by caller; stage; bar; prio-MFMA; bar
#define PHASE(q, AF, BF, STMT) do { \
    STMT; \
    RBAR(); \
    __builtin_amdgcn_s_setprio(1); \
    MM(q, AF, BF); \
    __builtin_amdgcn_s_setprio(0); \
    RBAR(); \
  } while (0)

__device__ __forceinline__ void gemm256_core(
    const ushort_t* __restrict__ A, const ushort_t* __restrict__ Bt,
    int lda, int ldb, int kdim,
    ushort_t* As, ushort_t* Bs, floatx4 acc[4][4][2])
{
  const int t = threadIdx.x;
  const int w = t >> 6, l = t & 63;
  const int l15 = l & 15, lq = l >> 4;
  const int wq_r = w >> 2, wq_c = w & 3;

  const int r0 = t >> 3, c0 = t & 7;
  const ushort_t* gA = A + (size_t)r0 * lda + ((c0 ^ (r0 & 7)) << 3);
  const ushort_t* gB = Bt + (size_t)r0 * ldb + ((c0 ^ (r0 & 7)) << 3);
  const size_t a64 = (size_t)64 * lda, b64 = (size_t)64 * ldb;
  const size_t a128 = (size_t)128 * lda, b128 = (size_t)128 * ldb;
  char* sAh = (char*)As + (w << 10);
  char* sBh = (char*)Bs + (w << 10);

  const int aoff0 = ((wq_r << 6) + l15) << 7;
  const int boff0 = ((wq_c << 5) + l15) << 7;
  const int l7 = l15 & 7;
  const int swz0 = (lq ^ l7) << 4;
  const int swz1 = ((4 + lq) ^ l7) << 4;

  const int nt = kdim >> 6;   // even for all our shapes (8/16/32)

#pragma unroll
  for (int q = 0; q < 4; ++q)
#pragma unroll
    for (int i = 0; i < 4; ++i)
#pragma unroll
      for (int j = 0; j < 2; ++j)
        acc[q][i][j] = (floatx4){0.f, 0.f, 0.f, 0.f};

  // prologue: tile0 all 4 halves + A0/B0 of tile1; keep newest 2 in flight
  STG_A(0, 0, 0);
  STG_B(0, 0, 0);
  STG_B(0, 1, 0);
  STG_A(0, 1, 0);
  STG_A(1, 0, 1);
  STG_B(1, 0, 1);
  asm volatile("s_waitcnt vmcnt(4)" ::: "memory");
  RBAR();

  bf16x8 a[4][2], b0[2][2], b1[2][2];

#pragma unroll 1
  for (int T = 0; T < nt; T += 2) {
    const bool more = (T + 2 < nt);
    // ---- ph0: tile T q(0,0); stage B1(T+1)
    LD_A2(a, 0, 0);
    LD_B2(b0, 0, 0);
    PHASE(0, a, b0, STG_B(1, 1, T + 1));
    // ---- ph1: tile T q(0,1); stage A1(T+1)
    LD_B2(b1, 0, 1);
    PHASE(1, a, b1, STG_A(1, 1, T + 1));
    // ---- ph2: tile T q(1,1); stage A0(T+2)
    LD_A2(a, 0, 1);
    PHASE(2, a, b1, if (more) STG_A(0, 0, T + 2));
    // ---- ph3: tile T q(1,0); stage B0(T+2); boundary vmcnt
    {
      if (more) STG_B(0, 0, T + 2);
      RBAR();
      __builtin_amdgcn_s_setprio(1);
      MM(3, a, b0);
      __builtin_amdgcn_s_setprio(0);
      if (more) asm volatile("s_waitcnt vmcnt(4)" ::: "memory");
      else      asm volatile("s_waitcnt vmcnt(0)" ::: "memory");
      RBAR();
    }
    // ---- ph4: tile T+1 q(0,0); stage B1(T+2)
    LD_A2(a, 1, 0);
    LD_B2(b0, 1, 0);
    PHASE(0, a, b0, if (more) STG_B(0, 1, T + 2));
    // ---- ph5: tile T+1 q(0,1); stage A1(T+2)
    LD_B2(b1, 1, 1);
    PHASE(1, a, b1, if (more) STG_A(0, 1, T + 2));
    // ---- ph6: tile T+1 q(1,1); stage A0(T+3)
    LD_A2(a, 1, 1);
    PHASE(2, a, b1, if (more) STG_A(1, 0, T + 3));
    // ---- ph7: tile T+1 q(1,0); stage B0(T+3); boundary vmcnt
    {
      if (more) STG_B(1, 0, T + 3);
      RBAR();
      __builtin_amdgcn_s_setprio(1);
      MM(3, a, b0);
      __builtin_amdgcn_s_setprio(0);
      if (more) asm volatile("s_waitcnt vmcnt(4)" ::: "memory");
      else      asm volatile("s_waitcnt vmcnt(0)" ::: "memory");
      RBAR();
    }
  }
}

// ---------- fp32 -> bf16 bulk convert into g_ws ----------
__global__ __launch_bounds__(256) void convert_f32_bf16(
    const float* __restrict__ src, size_t dstOff, int n)
{
  ushort_t* dst = (ushort_t*)(g_ws + dstOff);
  int i = (blockIdx.x * 256 + threadIdx.x) * 4;
  if (i >= n) return;
  float4 v = *(const float4*)(src + i);
  ushort_t o[4] = {f2bf(v.x), f2bf(v.y), f2bf(v.z), f2bf(v.w)};
  *(uint2*)(dst + i) = *(const uint2*)o;
}

// ---------- fp32 [R][C] -> bf16 [C][R] transpose into g_ws, batched over z ----
__global__ __launch_bounds__(256) void transpose_f32_bf16(
    const float* __restrict__ src, size_t dstOff, int R, int C)
{
  __shared__ ushort_t tile[32][33];
  ushort_t* dst = (ushort_t*)(g_ws + dstOff) + (size_t)blockIdx.z * R * C;
  src += (size_t)blockIdx.z * R * C;
  int r0 = blockIdx.y * 32, c0 = blockIdx.x * 32;
  int tx = threadIdx.x & 31, ty = threadIdx.x >> 5;
  for (int i = ty; i < 32; i += 8)
    tile[i][tx] = f2bf(src[(size_t)(r0 + i) * C + (c0 + tx)]);
  __syncthreads();
  for (int i = ty; i < 32; i += 8)
    dst[(size_t)(c0 + i) * R + (r0 + tx)] = tile[tx][i];
}

// ---------- merged Wq/Wk/Wv transpose: z in [0,24) ----------
__global__ __launch_bounds__(256) void transpose_w3(
    const float* __restrict__ Wq, const float* __restrict__ Wk,
    const float* __restrict__ Wv)
{
  __shared__ ushort_t tile[32][33];
  const int z = blockIdx.z;
  const int sel = z >> 3, h = z & 7;
  const float* src = ((sel == 0) ? Wq : (sel == 1) ? Wk : Wv)
                     + (size_t)h * DIN * DH;
  ushort_t* dst = (ushort_t*)(g_ws + ((sel == 0) ? WQT_OFF
                                      : (sel == 1) ? WKT_OFF : WVT_OFF))
                  + (size_t)h * DIN * DH;
  int r0 = blockIdx.y * 32, c0 = blockIdx.x * 32;
  int tx = threadIdx.x & 31, ty = threadIdx.x >> 5;
  for (int i = ty; i < 32; i += 8)
    tile[i][tx] = f2bf(src[(size_t)(r0 + i) * DH + (c0 + tx)]);
  __syncthreads();
  for (int i = ty; i < 32; i += 8)
    dst[(size_t)(c0 + i) * DIN + (r0 + tx)] = tile[tx][i];
}

// ---------- zero lsum (32*2048 fp32 = 256 KiB), once per launch ----------
__global__ __launch_bounds__(256) void zero_lsum()
{
  float* lsum = (float*)(g_ws + LSUM_OFF);
  int i = (blockIdx.x * 256 + threadIdx.x) * 4;
  *(float4*)(lsum + i) = (float4){0.f, 0.f, 0.f, 0.f};
}

// ---------- QKV projection (256² core): z in [0,96) ----------
__global__ __launch_bounds__(512, 2) void qkv_gemm(
    const float* __restrict__ bq, const float* __restrict__ bk,
    const float* __restrict__ bv)
{
  __shared__ __align__(16) ushort_t SH[65536];   // 128 KiB
  ushort_t* As = SH;
  ushort_t* Bs = SH + 32768;
  const int z = blockIdx.z;
  const int bh = z & 31, sel = z >> 5, b = bh >> 3, h = bh & 7;
  const size_t wOff = (sel == 0) ? WQT_OFF : (sel == 1) ? WKT_OFF : WVT_OFF;
  const float* bias = ((sel == 0) ? bq : (sel == 1) ? bk : bv) + h * DH;
  const int tileM = blockIdx.y * 256, tileN = blockIdx.x * 256;

  const ushort_t* A  = (const ushort_t*)(g_ws + XBF_OFF)
                       + ((size_t)b * S_LEN + tileM) * DIN;
  const ushort_t* Bt = (const ushort_t*)(g_ws + wOff)
                       + ((size_t)h * DH + tileN) * DIN;
  floatx4 acc[4][4][2];
  gemm256_core(A, Bt, DIN, DIN, DIN, As, Bs, acc);

  const int t = threadIdx.x, w = t >> 6, l = t & 63;
  const int l15 = l & 15, lq = l >> 4;
  const int wq_r = w >> 2, wq_c = w & 3;
  const int QM[4] = {0, 0, 1, 1}, QN[4] = {0, 1, 1, 0};

  if (sel == 2) {
    // ---- VT transpose-bounce (r3-proven: fixes 4KB-stride scatter) ----
    char* SB = (char*)SH;
    BBAR();   // core's reads all done; safe to reuse SH
#pragma unroll
    for (int q = 0; q < 4; ++q) {
#pragma unroll
      for (int j = 0; j < 2; ++j) {
        const int nl = QN[q] * 128 + wq_c * 32 + j * 16 + l15;
        const float bsn = bias[tileN + nl];
#pragma unroll
        for (int i = 0; i < 4; ++i) {
          const int ml = QM[q] * 128 + wq_r * 64 + i * 16 + lq * 4;
          ushort_t pk[4];
#pragma unroll
          for (int r = 0; r < 4; ++r) pk[r] = f2bf(acc[q][i][j][r] + bsn);
          const int byte = nl * 512 + (((ml >> 3) ^ (nl & 7)) << 4) + (ml & 7) * 2;
          *(uint2*)(SB + byte) = *(const uint2*)pk;
        }
      }
    }
    BBAR();
    ushort_t* VTb = (ushort_t*)(g_ws + VT_OFF)
                    + ((size_t)bh * DH + tileN) * S_LEN + tileM;
#pragma unroll
    for (int s = 0; s < 16; ++s) {
      const int nl = (w << 5) + (s << 1) + (l >> 5);
      const int c  = l & 31;
      const uint4 v = *(const uint4*)(SB + nl * 512 + ((c ^ (nl & 7)) << 4));
      *(uint4*)(VTb + (size_t)nl * S_LEN + c * 8) = v;
    }
  } else {
    // ---- Q/K direct stores (r9 proved bouncing these is a regression) ----
    ushort_t* Db = (ushort_t*)(g_ws + ((sel == 0) ? Q_OFF : K_OFF));
#pragma unroll
    for (int q = 0; q < 4; ++q) {
#pragma unroll
      for (int j = 0; j < 2; ++j) {
        const int n = tileN + QN[q] * 128 + wq_c * 32 + j * 16 + l15;
        const float bsn = bias[n];
#pragma unroll
        for (int i = 0; i < 4; ++i) {
#pragma unroll
          for (int r = 0; r < 4; ++r) {
            const int m = tileM + QM[q] * 128 + wq_r * 64 + i * 16 + lq * 4 + r;
            Db[((size_t)bh * S_LEN + m) * DH + n] = f2bf(acc[q][i][j][r] + bsn);
          }
        }
      }
    }
  }
}

// ---------- scores + masked exp + fused row-sum, head chunk [c0, c0+16) ----
__global__ __launch_bounds__(512, 2) void scores_kernel(
    const int* __restrict__ mask, int c0)
{
  __shared__ __align__(16) ushort_t SH[65536];
  ushort_t* As = SH;
  ushort_t* Bs = SH + 32768;
  const int hl = blockIdx.z, bh = c0 + hl, b = bh >> 3;
  const int tileM = blockIdx.y * 256, tileN = blockIdx.x * 256;

  const ushort_t* A  = (const ushort_t*)(g_ws + Q_OFF)
                       + ((size_t)bh * S_LEN + tileM) * DH;
  const ushort_t* Bt = (const ushort_t*)(g_ws + K_OFF)
                       + ((size_t)bh * S_LEN + tileN) * DH;
  floatx4 acc[4][4][2];
  gemm256_core(A, Bt, DH, DH, DH, As, Bs, acc);

  const float scale = 0.04419417382415922f;  // 1/sqrt(512)
  const int t = threadIdx.x, w = t >> 6, l = t & 63;
  const int l15 = l & 15, lq = l >> 4;
  const int wq_r = w >> 2, wq_c = w & 3;
  const int QM[4] = {0, 0, 1, 1}, QN[4] = {0, 1, 1, 0};
  ushort_t* Pp = (ushort_t*)(g_ws + P_OFF) + (size_t)hl * S_LEN * S_LEN;
  const int* mask_b = mask + (size_t)b * S_LEN;
  float* lsum = (float*)(g_ws + LSUM_OFF);   // [32][2048], global bh index

  float rsum[2][4][4];
#pragma unroll
  for (int qm = 0; qm < 2; ++qm)
#pragma unroll
    for (int i = 0; i < 4; ++i)
#pragma unroll
      for (int r = 0; r < 4; ++r) rsum[qm][i][r] = 0.f;

#pragma unroll
  for (int q = 0; q < 4; ++q) {
#pragma unroll
    for (int j = 0; j < 2; ++j) {
      const int n = tileN + QN[q] * 128 + wq_c * 32 + j * 16 + l15;
      const int mv = mask_b[n];
#pragma unroll
      for (int i = 0; i < 4; ++i) {
#pragma unroll
        for (int r = 0; r < 4; ++r) {
          const int m = tileM + QM[q] * 128 + wq_r * 64 + i * 16 + lq * 4 + r;
          float s = fminf(acc[q][i][j][r] * scale, 30.f);  // clamp: no inf
          const float p = mv ? __expf(s) : 0.f;
          rsum[QM[q]][i][r] += p;
          Pp[(size_t)m * S_LEN + n] = f2bf(p);
        }
      }
    }
  }
#pragma unroll
  for (int qm = 0; qm < 2; ++qm) {
#pragma unroll
    for (int i = 0; i < 4; ++i) {
#pragma unroll
      for (int r = 0; r < 4; ++r) {
        float v = rsum[qm][i][r];
        v += __shfl_xor(v, 1);
        v += __shfl_xor(v, 2);
        v += __shfl_xor(v, 4);
        v += __shfl_xor(v, 8);
        if (l15 == 0) {
          const int m = tileM + qm * 128 + wq_r * 64 + i * 16 + lq * 4 + r;
          atomicAdd(&lsum[(size_t)bh * S_LEN + m], v);
        }
      }
    }
  }
}

// ---------- P*V, divide by rowsum, store cat-layout O ----------
__global__ __launch_bounds__(512, 2) void pv_kernel(int c0)
{
  __shared__ __align__(16) ushort_t SH[65536];
  ushort_t* As = SH;
  ushort_t* Bs = SH + 32768;
  const int hl = blockIdx.z, bh = c0 + hl, b = bh >> 3, h = bh & 7;
  const int tileM = blockIdx.y * 256, tileN = blockIdx.x * 256;

  const ushort_t* A  = (const ushort_t*)(g_ws + P_OFF)
                       + (size_t)hl * S_LEN * S_LEN + (size_t)tileM * S_LEN;
  const ushort_t* Bt = (const ushort_t*)(g_ws + VT_OFF)
                       + ((size_t)bh * DH + tileN) * S_LEN;
  floatx4 acc[4][4][2];
  gemm256_core(A, Bt, S_LEN, S_LEN, S_LEN, As, Bs, acc);

  const float* lsum = (const float*)(g_ws + LSUM_OFF);
  ushort_t* Ob = (ushort_t*)(g_ws + O_OFF);
  const int t = threadIdx.x, w = t >> 6, l = t & 63;
  const int l15 = l & 15, lq = l >> 4;
  const int wq_r = w >> 2, wq_c = w & 3;
  const int QM[4] = {0, 0, 1, 1}, QN[4] = {0, 1, 1, 0};
#pragma unroll
  for (int q = 0; q < 4; ++q) {
#pragma unroll
    for (int i = 0; i < 4; ++i) {
#pragma unroll
      for (int r = 0; r < 4; ++r) {
        const int m = tileM + QM[q] * 128 + wq_r * 64 + i * 16 + lq * 4 + r;
        const float lv = lsum[(size_t)bh * S_LEN + m];
        const float inv = (lv > 1e-20f) ? 1.0f / lv : 0.f;
#pragma unroll
        for (int j = 0; j < 2; ++j) {
          const int n = tileN + QN[q] * 128 + wq_c * 32 + j * 16 + l15;
          Ob[((size_t)b * S_LEN + m) * HP + h * DH + n] =
              f2bf(acc[q][i][j][r] * inv);
        }
      }
    }
  }
}

// ---------- out projection, 256² core + split-K=4, plain-store partials ----
// part[ks][8192][512] = Ob[.][ks*1024 : (ks+1)*1024] * WpT^T-slice.
// No atomics (r10's 16.8M fp32 atomicAdds serialize through L2 atomic units);
// reduce_out sums the 4 partials + bias.
__global__ __launch_bounds__(512, 2) void proj_kernel()
{
  __shared__ __align__(16) ushort_t SH[65536];
  ushort_t* As = SH;
  ushort_t* Bs = SH + 32768;
  const int tileM = blockIdx.y * 256, tileN = blockIdx.x * 256;
  const int ks = blockIdx.z;

  const ushort_t* A  = (const ushort_t*)(g_ws + O_OFF)
                       + (size_t)tileM * HP + ks * 1024;
  const ushort_t* Bt = (const ushort_t*)(g_ws + WPT_OFF)
                       + (size_t)tileN * HP + ks * 1024;
  floatx4 acc[4][4][2];
  gemm256_core(A, Bt, HP, HP, 1024, As, Bs, acc);

  float* part = (float*)(g_ws + PART_OFF)
                + (size_t)ks * NBAT * S_LEN * DH;
  const int t = threadIdx.x, w = t >> 6, l = t & 63;
  const int l15 = l & 15, lq = l >> 4;
  const int wq_r = w >> 2, wq_c = w & 3;
  const int QM[4] = {0, 0, 1, 1}, QN[4] = {0, 1, 1, 0};
#pragma unroll
  for (int q = 0; q < 4; ++q) {
#pragma unroll
    for (int j = 0; j < 2; ++j) {
      const int n = tileN + QN[q] * 128 + wq_c * 32 + j * 16 + l15;
#pragma unroll
      for (int i = 0; i < 4; ++i) {
#pragma unroll
        for (int r = 0; r < 4; ++r) {
          const int m = tileM + QM[q] * 128 + wq_r * 64 + i * 16 + lq * 4 + r;
          part[(size_t)m * DH + n] = acc[q][i][j][r];
        }
      }
    }
  }
}

// ---------- reduce 4 partials + bias -> fp32 out ----------
__global__ __launch_bounds__(256) void reduce_out(
    const float* __restrict__ bp, float* __restrict__ out)
{
  const float* part = (const float*)(g_ws + PART_OFF);
  const size_t N = (size_t)NBAT * S_LEN * DH;
  const size_t j = ((size_t)blockIdx.x * 256 + threadIdx.x) * 4;
  const float4 s0 = *(const float4*)(part + j);
  const float4 s1 = *(const float4*)(part + N + j);
  const float4 s2 = *(const float4*)(part + 2 * N + j);
  const float4 s3 = *(const float4*)(part + 3 * N + j);
  const float4 bv = *(const float4*)(bp + (j & (DH - 1)));
  float4 o;
  o.x = s0.x + s1.x + s2.x + s3.x + bv.x;
  o.y = s0.y + s1.y + s2.y + s3.y + bv.y;
  o.z = s0.z + s1.z + s2.z + s3.z + bv.z;
  o.w = s0.w + s1.w + s2.w + s3.w + bv.w;
  *(float4*)(out + j) = o;
}

// ---------- host ----------
extern "C" void kernel_launch(void* const* d_in, const int* in_sizes, int n_in,
                              void* d_out, int out_size, void* d_ws, size_t ws_size,
                              hipStream_t stream) {
  const float* x  = (const float*)d_in[0];
  const int*   msk= (const int*)d_in[1];
  const float* Wq = (const float*)d_in[2];
  const float* bq = (const float*)d_in[3];
  const float* Wk = (const float*)d_in[4];
  const float* bk = (const float*)d_in[5];
  const float* Wv = (const float*)d_in[6];
  const float* bv = (const float*)d_in[7];
  const float* Wp = (const float*)d_in[8];
  const float* bp = (const float*)d_in[9];
  float* out = (float*)d_out;

  // x -> bf16 (all batches)
  convert_f32_bf16<<<dim3(NBAT * S_LEN * DIN / 1024), 256, 0, stream>>>(
      x, XBF_OFF, NBAT * S_LEN * DIN);

  // weight transposes (fp32 -> bf16): Wq/Wk/Wv merged; Wp separate shape
  transpose_w3<<<dim3(16, 16, 24), 256, 0, stream>>>(Wq, Wk, Wv);
  transpose_f32_bf16<<<dim3(16, 128, 1), 256, 0, stream>>>(Wp, WPT_OFF, HP, DH);

  // zero all 32 heads' lsum once
  zero_lsum<<<dim3(64), 256, 0, stream>>>();

  // Q/K/V^T for all 32 (b,h): 256² tiles -> grid (2, 8, 96)
  qkv_gemm<<<dim3(2, 8, 3 * NBH), 512, 0, stream>>>(bq, bk, bv);

  // attention in chunks of 16 heads (P chunk = 128 MiB, L3-resident)
  for (int c0 = 0; c0 < NBH; c0 += 16) {
    scores_kernel<<<dim3(8, 8, 16), 512, 0, stream>>>(msk, c0);
    pv_kernel<<<dim3(2, 8, 16), 512, 0, stream>>>(c0);
  }

  // final projection: split-K=4 plain-store partials, then reduce + bias
  proj_kernel<<<dim3(2, 32, 4), 512, 0, stream>>>();
  reduce_out<<<dim3(NBAT * S_LEN * DH / 1024), 256, 0, stream>>>(bp, out);
}